// Round 18
// baseline (63.024 us; speedup 1.0000x reference)
//
#include <hip/hip_runtime.h>

// Multi-Scale Deformable Attention forward, fp32 in/out.
// B=1, Q=19947, heads=8, D=32, L=4, P=4.
// Levels: (100,150),(50,75),(25,38),(13,19); starts 0,15000,18750,19700.
//
// - Head-per-XCD: blockIdx.x%8 == head rides round-robin XCD dispatch;
//   fp16 value slice per head L2-resident (verified FETCH 315->25 MB).
// - R18: x-paired row layout. Row t = tokens {t,t+1} channel-interleaved
//   [ch_grp][slot][8ch] = 128 B aligned. Bilinear x-corners are always
//   {i00, i00+1} -> ONE row read serves both corners. 16 lanes/pair
//   (2 halves x 4 ch-grp x 2 slot); per sample each lane does one 16 B
//   load per y-row: wave inst = 8 dense 128 B rows (8 line-touches vs
//   16). L2 requests halve: 10.2M -> 5.1M. x-clamp folded into slot
//   coefficients. One-shot shfl_xor(1)/(8) combine; 128 B/pair store.
// - Tiers: ws >= 20.4 MB -> paired layout; >= 10.2 MB -> R17 kernel
//   (proven 47 us); else fp32 direct.
// - Rejected: metadata dedup (R11 LDS, R12 shfl), sw-pipeline (R16),
//   pure TLP scaling (R17) - all neutral or worse.

typedef float    f32x4 __attribute__((ext_vector_type(4)));
typedef float    f32x8 __attribute__((ext_vector_type(8)));
typedef _Float16 f16x8 __attribute__((ext_vector_type(8)));

constexpr int HEADS = 8;
constexpr int DCH   = 32;
constexpr int NSP   = 16;
constexpr int NQ    = 19947;
constexpr int HSTR1 = NQ * DCH;        // fp16 elems per head slice (R17 layout)
constexpr int HSTR2 = NQ * 64;         // fp16 elems per head slice (paired rows)
constexpr int NVAL  = NQ * HEADS * DCH;

// ---- cvt A: paired-row layout [h][row t][ch_grp][slot][8ch] ----------------
__global__ __launch_bounds__(256)
void cvt_pair_kernel(const float* __restrict__ value, _Float16* __restrict__ ws)
{
    const int h = blockIdx.x & 7;                       // head == XCD id
    const int i = (blockIdx.x >> 3) * 256 + threadIdx.x;
    if (i >= NQ * 4) return;
    const int jj = i & 3;
    const int t  = i >> 2;
    const float* src = value + (size_t)t * 256 + h * 32 + jj * 8;
    const f32x4 a = __builtin_nontemporal_load((const f32x4*)src);
    const f32x4 b = __builtin_nontemporal_load((const f32x4*)(src + 4));
    const f32x8 v = {a.x, a.y, a.z, a.w, b.x, b.y, b.z, b.w};
    const f16x8 o = __builtin_convertvector(v, f16x8);
    _Float16* base = ws + (size_t)h * HSTR2;
    *(f16x8*)(base + (size_t)t * 64 + jj * 16) = o;                 // row t slot 0
    if (t > 0)
        *(f16x8*)(base + (size_t)(t - 1) * 64 + jj * 16 + 8) = o;   // row t-1 slot 1
    if (t == NQ - 1) {
        const f16x8 z = {};
        *(f16x8*)(base + (size_t)t * 64 + jj * 16 + 8) = z;         // pad slot
    }
}

// ---- cvt B: plain head-major [h][tok][32ch] (R17 fallback) -----------------
__global__ __launch_bounds__(256)
void cvt_kernel(const float* __restrict__ value, _Float16* __restrict__ ws)
{
    const int h = blockIdx.x & 7;
    const int i = (blockIdx.x >> 3) * 256 + threadIdx.x;
    if (i >= NQ * 4) return;
    const int c8  = i & 3;
    const int tok = i >> 2;
    const float* src = value + (size_t)tok * 256 + h * 32 + c8 * 8;
    const f32x4 a = __builtin_nontemporal_load((const f32x4*)src);
    const f32x4 b = __builtin_nontemporal_load((const f32x4*)(src + 4));
    const f32x8 v = {a.x, a.y, a.z, a.w, b.x, b.y, b.z, b.w};
    *(f16x8*)(ws + (size_t)h * HSTR1 + (size_t)tok * 32 + c8 * 8) =
        __builtin_convertvector(v, f16x8);
}

// ---- R18 main kernel: paired rows, 16 lanes/pair ---------------------------
__global__ __launch_bounds__(256)
void msda_pair_kernel(const _Float16* __restrict__ ws,
                      const float* __restrict__ loc,
                      const float* __restrict__ attw,
                      float* __restrict__ out)
{
    constexpr int QPB = 16;            // pairs per block (256 thr / 16 lanes)
    __shared__ float s_loc[QPB][33];   // pre-scaled x,y
    __shared__ float s_aw [QPB][17];

    const int h    = blockIdx.x & 7;          // head == XCD id
    const int qblk = blockIdx.x >> 3;
    const int q0   = qblk * QPB;
    const int t    = threadIdx.x;

    // ---- staging: loc 128 chunks, attw 64 chunks ----
    if (t < 128) {
        const int sub = t >> 3, j = t & 7;    // chunk j = samples 2j,2j+1
        const int q = q0 + sub;
        if (q < NQ) {
            const f32x4 v = __builtin_nontemporal_load(
                (const f32x4*)(loc + ((size_t)(q * HEADS + h)) * (NSP * 2) + j * 4));
            const int l = j >> 1;
            const float fW = (l == 0) ? 150.f : (l == 1) ? 75.f : (l == 2) ? 38.f : 19.f;
            const float fH = (l == 0) ? 100.f : (l == 1) ? 50.f : (l == 2) ? 25.f : 13.f;
            s_loc[sub][j * 4 + 0] = v.x * fW - 0.5f;
            s_loc[sub][j * 4 + 1] = v.y * fH - 0.5f;
            s_loc[sub][j * 4 + 2] = v.z * fW - 0.5f;
            s_loc[sub][j * 4 + 3] = v.w * fH - 0.5f;
        }
    } else if (t < 192) {
        const int u = t - 128;
        const int sub = u >> 2, j = u & 3;
        const int q = q0 + sub;
        if (q < NQ) {
            const f32x4 w = __builtin_nontemporal_load(
                (const f32x4*)(attw + ((size_t)(q * HEADS + h)) * NSP + j * 4));
            s_aw[sub][j * 4 + 0] = w.x;
            s_aw[sub][j * 4 + 1] = w.y;
            s_aw[sub][j * 4 + 2] = w.z;
            s_aw[sub][j * 4 + 3] = w.w;
        }
    }
    __syncthreads();

    const int sub  = t >> 4;              // pair in block
    const int ll   = t & 15;
    const int half = ll >> 3;             // sample half: 0 -> sp 0-7, 1 -> 8-15
    const int g    = (ll >> 1) & 3;       // channel group (8 ch)
    const int s    = ll & 1;              // x slot
    const int q    = q0 + sub;
    if (q >= NQ) return;

    const _Float16* vf = ws + (size_t)h * HSTR2 + g * 16 + s * 8;

    f32x8 acc = {0.f, 0.f, 0.f, 0.f, 0.f, 0.f, 0.f, 0.f};
    const int sp0 = half * 8;

#pragma unroll
    for (int u = 0; u < 8; ++u) {
        const int sp = sp0 + u;
        const int l  = sp >> 2;
        const int W = (l == 0) ? 150 : (l == 1) ? 75 : (l == 2) ? 38 : 19;
        const int H = (l == 0) ? 100 : (l == 1) ? 50 : (l == 2) ? 25 : 13;
        const int S = (l == 0) ? 0 : (l == 1) ? 15000 : (l == 2) ? 18750 : 19700;

        const float x  = s_loc[sub][sp * 2 + 0];
        const float y  = s_loc[sub][sp * 2 + 1];
        const float aw = s_aw[sub][sp];

        const float x0f = floorf(x);
        const float y0f = floorf(y);
        const float wx1 = x - x0f;
        const float wy1 = y - y0f;
        const float wx0 = 1.f - wx1;
        const float wy0 = 1.f - wy1;
        const int x0 = (int)x0f, y0 = (int)y0f;   // in [-1, W-1]
        const int x1 = x0 + 1,   y1 = y0 + 1;     // in [0, W]

        const float wx0m = ((unsigned)x0 < (unsigned)W) ? wx0 : 0.f;
        const float wx1m = ((unsigned)x1 < (unsigned)W) ? wx1 : 0.f;
        const float wy0m = ((unsigned)y0 < (unsigned)H) ? aw * wy0 : 0.f;
        const float wy1m = ((unsigned)y1 < (unsigned)H) ? aw * wy1 : 0.f;
        const float c00 = wy0m * wx0m;
        const float c01 = wy0m * wx1m;
        const float c10 = wy1m * wx0m;
        const float c11 = wy1m * wx1m;

        const int cx0 = max(x0, 0), cx1 = min(x1, W - 1);
        const int cy0 = max(y0, 0), cy1 = min(y1, H - 1);
        const bool xi = cx1 > cx0;        // x-interior (slot1 = corner x1)

        // per-slot coefficients: slot0 = token cx0, slot1 = token cx0+1
        const float fA = s ? (xi ? c01 : 0.f) : (xi ? c00 : c00 + c01);
        const float fB = s ? (xi ? c11 : 0.f) : (xi ? c10 : c10 + c11);

        const int rb0 = S + cy0 * W + cx0;
        const int rb1 = S + cy1 * W + cx0;

        const f16x8 g0 = *(const f16x8*)(vf + (size_t)rb0 * 64);
        const f16x8 g1 = *(const f16x8*)(vf + (size_t)rb1 * 64);
#pragma unroll
        for (int k = 0; k < 8; ++k) {
            acc[k] += fA * (float)g0[k];
            acc[k] += fB * (float)g1[k];
        }
    }

    // combine x-slots then sample-halves (one-shot butterflies)
#pragma unroll
    for (int k = 0; k < 8; ++k) acc[k] += __shfl_xor(acc[k], 1);
#pragma unroll
    for (int k = 0; k < 8; ++k) acc[k] += __shfl_xor(acc[k], 8);

    if (half == 0) {   // 8 lanes x 16 B = contiguous 128 B per pair
        float* op = out + (size_t)(q * HEADS + h) * DCH + g * 8 + s * 4;
        const f32x4 part = s ? f32x4{acc[4], acc[5], acc[6], acc[7]}
                             : f32x4{acc[0], acc[1], acc[2], acc[3]};
        __builtin_nontemporal_store(part, (f32x4*)op);
    }
}

// ---- R17 kernel (mid-tier fallback, proven 47 us) --------------------------
template <bool F16>
__global__ __launch_bounds__(256)
void msda_fwd_kernel(const void* __restrict__ valuev,
                     const float* __restrict__ loc,
                     const float* __restrict__ attw,
                     float* __restrict__ out)
{
    constexpr int QPB = 32;
    __shared__ float s_loc[QPB][33];
    __shared__ float s_aw [QPB][17];

    const int h    = blockIdx.x & 7;
    const int qblk = blockIdx.x >> 3;
    const int q0   = qblk * QPB;
    const int t    = threadIdx.x;

    {
        const int sub = t >> 3, j = t & 7;
        const int q = q0 + sub;
        if (q < NQ) {
            const f32x4 v = __builtin_nontemporal_load(
                (const f32x4*)(loc + ((size_t)(q * HEADS + h)) * (NSP * 2) + j * 4));
            const int l = j >> 1;
            const float fW = (l == 0) ? 150.f : (l == 1) ? 75.f : (l == 2) ? 38.f : 19.f;
            const float fH = (l == 0) ? 100.f : (l == 1) ? 50.f : (l == 2) ? 25.f : 13.f;
            s_loc[sub][j * 4 + 0] = v.x * fW - 0.5f;
            s_loc[sub][j * 4 + 1] = v.y * fH - 0.5f;
            s_loc[sub][j * 4 + 2] = v.z * fW - 0.5f;
            s_loc[sub][j * 4 + 3] = v.w * fH - 0.5f;
        }
    }
    if (t < 128) {
        const int sub = t >> 2, j = t & 3;
        const int q = q0 + sub;
        if (q < NQ) {
            const f32x4 w = __builtin_nontemporal_load(
                (const f32x4*)(attw + ((size_t)(q * HEADS + h)) * NSP + j * 4));
            s_aw[sub][j * 4 + 0] = w.x;
            s_aw[sub][j * 4 + 1] = w.y;
            s_aw[sub][j * 4 + 2] = w.z;
            s_aw[sub][j * 4 + 3] = w.w;
        }
    }
    __syncthreads();

    const int sub  = t >> 3;
    const int jj   = t & 3;
    const int half = (t >> 2) & 1;
    const int q    = q0 + sub;
    if (q >= NQ) return;

    const _Float16* vf16 = (const _Float16*)valuev + (size_t)h * HSTR1 + jj * 8;
    const float*    vf32 = (const float*)valuev + h * DCH + jj * 8;

    f32x8 acc = {0.f, 0.f, 0.f, 0.f, 0.f, 0.f, 0.f, 0.f};
    const int sp0 = half * 8;

#pragma unroll
    for (int u = 0; u < 8; ++u) {
        const int sp = sp0 + u;
        const int l  = sp >> 2;
        const int W = (l == 0) ? 150 : (l == 1) ? 75 : (l == 2) ? 38 : 19;
        const int H = (l == 0) ? 100 : (l == 1) ? 50 : (l == 2) ? 25 : 13;
        const int S = (l == 0) ? 0 : (l == 1) ? 15000 : (l == 2) ? 18750 : 19700;
        const float x  = s_loc[sub][sp * 2 + 0];
        const float y  = s_loc[sub][sp * 2 + 1];
        const float aw = s_aw[sub][sp];
        const float x0f = floorf(x);
        const float y0f = floorf(y);
        const float wx1 = x - x0f;
        const float wy1 = y - y0f;
        const float wx0 = 1.f - wx1;
        const float wy0 = 1.f - wy1;
        const int x0 = (int)x0f, y0 = (int)y0f;
        const int x1 = x0 + 1,   y1 = y0 + 1;
        const float wx0m = ((unsigned)x0 < (unsigned)W) ? wx0 : 0.f;
        const float wx1m = ((unsigned)x1 < (unsigned)W) ? wx1 : 0.f;
        const float wy0m = ((unsigned)y0 < (unsigned)H) ? aw * wy0 : 0.f;
        const float wy1m = ((unsigned)y1 < (unsigned)H) ? aw * wy1 : 0.f;
        const f32x4 c = {wy0m * wx0m, wy0m * wx1m, wy1m * wx0m, wy1m * wx1m};
        const int cx0 = max(x0, 0), cx1 = min(x1, W - 1);
        const int cy0 = max(y0, 0), cy1 = min(y1, H - 1);
        const int r0 = S + cy0 * W;
        const int r1 = S + cy1 * W;
        const int i00 = r0 + cx0, i01 = r0 + cx1, i10 = r1 + cx0, i11 = r1 + cx1;

        if constexpr (F16) {
            const f16x8 g00 = *(const f16x8*)(vf16 + (size_t)i00 * 32);
            const f16x8 g01 = *(const f16x8*)(vf16 + (size_t)i01 * 32);
            const f16x8 g10 = *(const f16x8*)(vf16 + (size_t)i10 * 32);
            const f16x8 g11 = *(const f16x8*)(vf16 + (size_t)i11 * 32);
#pragma unroll
            for (int k = 0; k < 8; ++k) {
                acc[k] += c.x * (float)g00[k];
                acc[k] += c.y * (float)g01[k];
                acc[k] += c.z * (float)g10[k];
                acc[k] += c.w * (float)g11[k];
            }
        } else {
            const f32x4 a0 = *(const f32x4*)(vf32 + ((size_t)i00 << 8));
            const f32x4 a1 = *(const f32x4*)(vf32 + ((size_t)i00 << 8) + 4);
            const f32x4 b0 = *(const f32x4*)(vf32 + ((size_t)i01 << 8));
            const f32x4 b1 = *(const f32x4*)(vf32 + ((size_t)i01 << 8) + 4);
            const f32x4 c0 = *(const f32x4*)(vf32 + ((size_t)i10 << 8));
            const f32x4 c1 = *(const f32x4*)(vf32 + ((size_t)i10 << 8) + 4);
            const f32x4 d0 = *(const f32x4*)(vf32 + ((size_t)i11 << 8));
            const f32x4 d1 = *(const f32x4*)(vf32 + ((size_t)i11 << 8) + 4);
#pragma unroll
            for (int k = 0; k < 4; ++k) {
                acc[k]     += c.x * a0[k] + c.y * b0[k] + c.z * c0[k] + c.w * d0[k];
                acc[k + 4] += c.x * a1[k] + c.y * b1[k] + c.z * c1[k] + c.w * d1[k];
            }
        }
    }

#pragma unroll
    for (int k = 0; k < 8; ++k) acc[k] += __shfl_xor(acc[k], 4);

    float* op = out + (size_t)(q * HEADS + h) * DCH + jj * 8 + half * 4;
    const f32x4 part = half ? f32x4{acc[4], acc[5], acc[6], acc[7]}
                            : f32x4{acc[0], acc[1], acc[2], acc[3]};
    __builtin_nontemporal_store(part, (f32x4*)op);
}

extern "C" void kernel_launch(void* const* d_in, const int* in_sizes, int n_in,
                              void* d_out, int out_size, void* d_ws, size_t ws_size,
                              hipStream_t stream) {
    const float* value = (const float*)d_in[0];
    const float* loc   = (const float*)d_in[3];
    const float* attw  = (const float*)d_in[4];
    float* out = (float*)d_out;

    const size_t pair_bytes = (size_t)NQ * HEADS * 64 * sizeof(_Float16); // 20.4 MB
    const size_t f16_bytes  = (size_t)NVAL * sizeof(_Float16);            // 10.2 MB
    const int cgrid = ((NQ * 4 + 255) / 256) * HEADS;                     // XCD-aligned

    if (ws_size >= pair_bytes) {
        _Float16* ws = (_Float16*)d_ws;
        cvt_pair_kernel<<<cgrid, 256, 0, stream>>>(value, ws);
        const int qblocks = (NQ + 15) / 16;           // 1247
        msda_pair_kernel<<<qblocks * HEADS, 256, 0, stream>>>(ws, loc, attw, out);
    } else if (ws_size >= f16_bytes) {
        _Float16* ws = (_Float16*)d_ws;
        cvt_kernel<<<cgrid, 256, 0, stream>>>(value, ws);
        const int qblocks = (NQ + 31) / 32;           // 624
        msda_fwd_kernel<true><<<qblocks * HEADS, 256, 0, stream>>>(ws, loc, attw, out);
    } else {
        const int qblocks = (NQ + 31) / 32;
        msda_fwd_kernel<false><<<qblocks * HEADS, 256, 0, stream>>>(value, loc, attw, out);
    }
}

// Round 19
// 54.583 us; speedup vs baseline: 1.1546x; 1.1546x over previous
//
#include <hip/hip_runtime.h>

// Multi-Scale Deformable Attention forward, fp32 in/out.
// B=1, Q=19947, heads=8, D=32, L=4, P=4.
// Levels: (100,150),(50,75),(25,38),(13,19); starts 0,15000,18750,19700.
//
// - Head-per-XCD: blockIdx.x%8 == head rides round-robin XCD dispatch;
//   fp16 paired-row slice (2.55 MB/XCD) L2-resident.
// - Paired slot-major rows (R18 memory shape, proven to halve TA lines):
//   row t = 128 B = [slot][ch_grp][8ch], slot s holds token t+s.
// - R19: metadata computed ONCE per (pair,sample) in phase 1 (256 items =
//   1/thread), stored in 8.4 KB LDS with per-slot x-clamp pre-resolved.
//   Phase 2 = 2 broadcast ds_reads + 2 gathers + 16 fma_mix per sample.
//   Kills R18's VALU wall (78% busy from 8x-redundant metadata).
// - Rejected: R11 (big-LDS meta, occupancy), R12 (shfl meta), R16 (sw
//   pipeline), R17 (pure TLP) - all neutral/worse.

typedef float    f32x2 __attribute__((ext_vector_type(2)));
typedef float    f32x4 __attribute__((ext_vector_type(4)));
typedef float    f32x8 __attribute__((ext_vector_type(8)));
typedef _Float16 f16x8 __attribute__((ext_vector_type(8)));

constexpr int HEADS = 8;
constexpr int DCH   = 32;
constexpr int NSP   = 16;
constexpr int NQ    = 19947;
constexpr int HSTR2 = NQ * 64;         // fp16 elems per head slice (paired rows)
constexpr int NVAL  = NQ * HEADS * DCH;

// ---- cvt: fp32 [tok][head][ch] -> fp16 paired slot-major rows --------------
// row t (128 B): elem offset = slot*32 + g*8; slot s = token t+s.
__global__ __launch_bounds__(256)
void cvt_pair_kernel(const float* __restrict__ value, _Float16* __restrict__ ws)
{
    const int h = blockIdx.x & 7;                       // head == XCD id
    const int i = (blockIdx.x >> 3) * 256 + threadIdx.x;
    if (i >= NQ * 4) return;
    const int g = i & 3;
    const int t = i >> 2;
    const float* src = value + (size_t)t * 256 + h * 32 + g * 8;
    const f32x4 a = __builtin_nontemporal_load((const f32x4*)src);
    const f32x4 b = __builtin_nontemporal_load((const f32x4*)(src + 4));
    const f32x8 v = {a.x, a.y, a.z, a.w, b.x, b.y, b.z, b.w};
    const f16x8 o = __builtin_convertvector(v, f16x8);
    _Float16* base = ws + (size_t)h * HSTR2;
    *(f16x8*)(base + (size_t)t * 64 + g * 8) = o;                   // row t slot0
    if (t > 0)
        *(f16x8*)(base + (size_t)(t - 1) * 64 + 32 + g * 8) = o;    // row t-1 slot1
    if (t == NQ - 1) {
        const f16x8 z = {};
        *(f16x8*)(base + (size_t)t * 64 + 32 + g * 8) = z;          // pad slot
    }
}

// ---- main kernel: phase-1 LDS metadata, phase-2 paired-row gather ----------
__global__ __launch_bounds__(256)
void msda_meta_kernel(const _Float16* __restrict__ ws,
                      const float* __restrict__ loc,
                      const float* __restrict__ attw,
                      float* __restrict__ out)
{
    constexpr int QPB = 16;            // pairs per block (256 thr / 16 lanes)
    constexpr int PSTR = NSP * 8 + 4;  // 132 words: pair stride -> banks 0,4,8,12
    __shared__ __align__(16) float s_meta[QPB][PSTR];   // 8.4 KB

    const int h    = blockIdx.x & 7;          // head == XCD id
    const int qblk = blockIdx.x >> 3;
    const int q0   = qblk * QPB;
    const int t    = threadIdx.x;

    // ---- phase 1: one metadata item per thread ----
    {
        const int pair = t >> 4, sp = t & 15;
        const int q = q0 + pair;
        if (q < NQ) {
            const size_t mb = (size_t)(q * HEADS + h);
            const f32x2 xy = __builtin_nontemporal_load(
                (const f32x2*)(loc + mb * (NSP * 2) + sp * 2));
            const float aw = __builtin_nontemporal_load(attw + mb * NSP + sp);

            const int l = sp >> 2;
            const float fW = (l == 0) ? 150.f : (l == 1) ? 75.f : (l == 2) ? 38.f : 19.f;
            const float fH = (l == 0) ? 100.f : (l == 1) ? 50.f : (l == 2) ? 25.f : 13.f;
            const int   W  = (l == 0) ? 150   : (l == 1) ? 75   : (l == 2) ? 38   : 19;
            const int   H  = (l == 0) ? 100   : (l == 1) ? 50   : (l == 2) ? 25   : 13;
            const int   S  = (l == 0) ? 0     : (l == 1) ? 15000: (l == 2) ? 18750: 19700;

            const float x = xy.x * fW - 0.5f;
            const float y = xy.y * fH - 0.5f;
            const float x0f = floorf(x);
            const float y0f = floorf(y);
            const float wx1 = x - x0f;
            const float wy1 = y - y0f;
            const float wx0 = 1.f - wx1;
            const float wy0 = 1.f - wy1;
            const int x0 = (int)x0f, y0 = (int)y0f;   // in [-1, W-1]
            const int x1 = x0 + 1,   y1 = y0 + 1;     // in [0, W]

            const float wx0m = ((unsigned)x0 < (unsigned)W) ? wx0 : 0.f;
            const float wx1m = ((unsigned)x1 < (unsigned)W) ? wx1 : 0.f;
            const float wy0m = ((unsigned)y0 < (unsigned)H) ? aw * wy0 : 0.f;
            const float wy1m = ((unsigned)y1 < (unsigned)H) ? aw * wy1 : 0.f;
            const float c00 = wy0m * wx0m;
            const float c01 = wy0m * wx1m;
            const float c10 = wy1m * wx0m;
            const float c11 = wy1m * wx1m;

            const int cx0 = max(x0, 0), cx1 = min(x1, W - 1);
            const int cy0 = max(y0, 0), cy1 = min(y1, H - 1);
            const bool xi = cx1 > cx0;     // slot1 really is corner x1

            // per-slot coefficients, x-clamp folded (slot0 = token cx0,
            // slot1 = token cx0+1). xi=0: everything lands on slot0.
            float* m = &s_meta[pair][sp * 8];
            m[0] = xi ? c00 : (c00 + c01);   // slot0, y-row0
            m[1] = xi ? c01 : 0.f;           // slot1, y-row0
            m[2] = xi ? c10 : (c10 + c11);   // slot0, y-row1
            m[3] = xi ? c11 : 0.f;           // slot1, y-row1
            int* mi = (int*)m;
            mi[4] = S + cy0 * W + cx0;       // row base y0
            mi[5] = S + cy1 * W + cx0;       // row base y1
        }
    }
    __syncthreads();

    // ---- phase 2: gather + accumulate ----
    const int pair = t >> 4;
    const int lane = t & 15;
    const int g    = lane & 3;            // ch group (8 ch)
    const int s    = (lane >> 2) & 1;     // token slot
    const int half = lane >> 3;           // sample half: 0 -> sp 0-7, 1 -> 8-15
    const int q    = q0 + pair;
    if (q >= NQ) return;

    const _Float16* vf = ws + (size_t)h * HSTR2 + s * 32 + g * 8;

    f32x8 acc = {0.f, 0.f, 0.f, 0.f, 0.f, 0.f, 0.f, 0.f};
    const int sp0 = half * 8;

#pragma unroll
    for (int u = 0; u < 8; ++u) {
        const float* m = &s_meta[pair][(sp0 + u) * 8];
        const f32x4 c = *(const f32x4*)m;            // a0,a1,b0,b1
        const int rb0 = ((const int*)m)[4];
        const int rb1 = ((const int*)m)[5];
        const float fA = s ? c.y : c.x;
        const float fB = s ? c.w : c.z;

        const f16x8 g0 = *(const f16x8*)(vf + (size_t)rb0 * 64);
        const f16x8 g1 = *(const f16x8*)(vf + (size_t)rb1 * 64);
#pragma unroll
        for (int k = 0; k < 8; ++k) {
            acc[k] += fA * (float)g0[k];
            acc[k] += fB * (float)g1[k];
        }
    }

    // combine slots (xor 4) then halves (xor 8)
#pragma unroll
    for (int k = 0; k < 8; ++k) acc[k] += __shfl_xor(acc[k], 4);
#pragma unroll
    for (int k = 0; k < 8; ++k) acc[k] += __shfl_xor(acc[k], 8);

    if (s == 0) {   // 8 lanes (half,g) x 16 B = contiguous 128 B per pair
        float* op = out + (size_t)(q * HEADS + h) * DCH + g * 8 + half * 4;
        const f32x4 part = half ? f32x4{acc[4], acc[5], acc[6], acc[7]}
                                : f32x4{acc[0], acc[1], acc[2], acc[3]};
        __builtin_nontemporal_store(part, (f32x4*)op);
    }
}

// ---- fp32 direct fallback (correctness only, tiny ws) ----------------------
__global__ __launch_bounds__(256)
void msda_f32_kernel(const float* __restrict__ value,
                     const float* __restrict__ loc,
                     const float* __restrict__ attw,
                     float* __restrict__ out)
{
    const int t    = blockIdx.x * blockDim.x + threadIdx.x;
    const int pair = t >> 3;
    const int d0   = (t & 7) * 4;
    if (pair >= NQ * HEADS) return;
    const int h = pair & 7;

    const float* locp = loc  + (size_t)pair * (NSP * 2);
    const float* awp  = attw + (size_t)pair * NSP;
    f32x4 acc = {0.f, 0.f, 0.f, 0.f};

#pragma unroll
    for (int sp = 0; sp < NSP; ++sp) {
        const int l = sp >> 2;
        const int W = (l == 0) ? 150 : (l == 1) ? 75 : (l == 2) ? 38 : 19;
        const int H = (l == 0) ? 100 : (l == 1) ? 50 : (l == 2) ? 25 : 13;
        const int S = (l == 0) ? 0 : (l == 1) ? 15000 : (l == 2) ? 18750 : 19700;
        const float x = locp[sp * 2] * W - 0.5f;
        const float y = locp[sp * 2 + 1] * H - 0.5f;
        const float aw = awp[sp];
        const float x0f = floorf(x), y0f = floorf(y);
        const float wx1 = x - x0f, wy1 = y - y0f;
        const float wx0 = 1.f - wx1, wy0 = 1.f - wy1;
        const int x0 = (int)x0f, y0 = (int)y0f, x1 = x0 + 1, y1 = y0 + 1;
        const float wx0m = ((unsigned)x0 < (unsigned)W) ? wx0 : 0.f;
        const float wx1m = ((unsigned)x1 < (unsigned)W) ? wx1 : 0.f;
        const float wy0m = ((unsigned)y0 < (unsigned)H) ? aw * wy0 : 0.f;
        const float wy1m = ((unsigned)y1 < (unsigned)H) ? aw * wy1 : 0.f;
        const int cx0 = max(x0, 0), cx1 = min(x1, W - 1);
        const int cy0 = max(y0, 0), cy1 = min(y1, H - 1);
        const size_t r0 = (size_t)(S + cy0 * W), r1 = (size_t)(S + cy1 * W);
        const f32x4 g00 = *(const f32x4*)(value + ((r0 + cx0) * 8 + h) * DCH + d0);
        const f32x4 g01 = *(const f32x4*)(value + ((r0 + cx1) * 8 + h) * DCH + d0);
        const f32x4 g10 = *(const f32x4*)(value + ((r1 + cx0) * 8 + h) * DCH + d0);
        const f32x4 g11 = *(const f32x4*)(value + ((r1 + cx1) * 8 + h) * DCH + d0);
        acc += g00 * (wy0m * wx0m);
        acc += g01 * (wy0m * wx1m);
        acc += g10 * (wy1m * wx0m);
        acc += g11 * (wy1m * wx1m);
    }
    *(f32x4*)(out + (size_t)pair * DCH + d0) = acc;
}

extern "C" void kernel_launch(void* const* d_in, const int* in_sizes, int n_in,
                              void* d_out, int out_size, void* d_ws, size_t ws_size,
                              hipStream_t stream) {
    const float* value = (const float*)d_in[0];
    const float* loc   = (const float*)d_in[3];
    const float* attw  = (const float*)d_in[4];
    float* out = (float*)d_out;

    const size_t pair_bytes = (size_t)NQ * HEADS * 64 * sizeof(_Float16); // 20.4 MB

    if (ws_size >= pair_bytes) {
        _Float16* ws = (_Float16*)d_ws;
        const int cgrid = ((NQ * 4 + 255) / 256) * HEADS;                 // XCD-aligned
        cvt_pair_kernel<<<cgrid, 256, 0, stream>>>(value, ws);
        const int qblocks = (NQ + 15) / 16;                               // 1247
        msda_meta_kernel<<<qblocks * HEADS, 256, 0, stream>>>(ws, loc, attw, out);
    } else {
        const int total = NQ * HEADS * 8;
        msda_f32_kernel<<<(total + 255) / 256, 256, 0, stream>>>(value, loc, attw, out);
    }
}